// Round 5
// baseline (193.963 us; speedup 1.0000x reference)
//
#include <hip/hip_runtime.h>
#include <hip/hip_bf16.h>
#include <stdint.h>

#define SZ 3072
#define D_ 1024
#define BB 4
#define TT 8192
#define NROWS (BB * TT)   // 32768

typedef unsigned short u16;
typedef __bf16 bf16x8 __attribute__((ext_vector_type(8)));
typedef float f32x4 __attribute__((ext_vector_type(4)));

// ---- helpers ---------------------------------------------------------------

__device__ __forceinline__ u16 f2bf(float f) {
    union { float f; uint32_t u; } c;
    c.f = f;
    uint32_t u = c.u;
    // round-to-nearest-even f32 -> bf16 (inputs are finite Gaussians, no NaN)
    uint32_t r = (u + 0x7FFFu + ((u >> 16) & 1u)) >> 16;
    return (u16)r;
}

__device__ __forceinline__ void gload_lds16(const void* g, void* l) {
    // async global->LDS, 16B per lane. LDS dest must be wave-uniform base + lane*16.
    __builtin_amdgcn_global_load_lds(
        (__attribute__((address_space(1))) void*)(void*)g,
        (__attribute__((address_space(3))) void*)l,
        16, 0, 0);
}

__device__ __forceinline__ int hash_pair(int cur, int prev) {
    int a = (cur % SZ) * (31337 % SZ);      // 31337 % 3072 = 617
    int b = (prev % SZ) * (1000003 % SZ);   // 1000003 % 3072 = 1603
    return (a + b) % SZ;                    // max sum < 7M, int32-safe
}

// ---- kernel 1: fp32 -> bf16 convert of tab and w_proj ----------------------

__global__ __launch_bounds__(256) void convert_kernel(
    const float* __restrict__ tab, const float* __restrict__ w,
    u16* __restrict__ tabb, u16* __restrict__ wb) {
    const int NT4 = SZ * D_ / 4;        // 786432 float4s from tab
    const int NTOT = NT4 + D_ * D_ / 4; // + 262144 from w
    int i = blockIdx.x * 256 + threadIdx.x;
    if (i >= NTOT) return;
    const float4* src;
    u16* dst;
    int o;
    if (i < NT4) { src = (const float4*)tab; dst = tabb; o = i; }
    else         { src = (const float4*)w;   dst = wb;   o = i - NT4; }
    float4 v = src[o];
    unsigned long long pack =
        (unsigned long long)f2bf(v.x) |
        ((unsigned long long)f2bf(v.y) << 16) |
        ((unsigned long long)f2bf(v.z) << 32) |
        ((unsigned long long)f2bf(v.w) << 48);
    *(unsigned long long*)&dst[o * 4] = pack;
}

// ---- kernel 2: hash indices ------------------------------------------------

__global__ __launch_bounds__(256) void hash_kernel(
    const int* __restrict__ t, int* __restrict__ idx) {
    int i = blockIdx.x * 256 + threadIdx.x;
    if (i >= NROWS) return;
    int j = i & (TT - 1);
    int cur = t[i];
    int prev = (j == 0) ? 0 : t[i - 1];
    idx[i] = hash_pair(cur, prev);
}

// ---- kernel 3: P[s,e] = sum_d tab[s,d] * w[e,d]  (bf16 MFMA, 128x128 tile) -

__global__ __launch_bounds__(256) void gemm_p_kernel(
    const u16* __restrict__ Ab,   // [SZ][D_] bf16 bits
    const u16* __restrict__ Wb,   // [D_][D_] bf16 bits
    float* __restrict__ P) {      // [SZ][D_]
    __shared__ __align__(16) u16 As[128][32];
    __shared__ __align__(16) u16 Ws[128][32];

    const int tid = threadIdx.x;
    const int brow = blockIdx.x >> 3;   // 24 row-tiles
    const int bcol = blockIdx.x & 7;    // 8 col-tiles
    const int row0 = brow << 7;
    const int col0 = bcol << 7;
    const int lane = tid & 63;
    const int w = tid >> 6;             // wave 0..3 in 2x2 grid of 64x64 tiles
    const int wr = (w >> 1) << 6;
    const int wc = (w & 1) << 6;
    const int lrow = lane & 15;         // fragment row (A) / col (B/D)
    const int k8 = (lane >> 4) << 3;    // fragment k-offset

    // staging: 512 16B-chunks per operand; chunk c -> row c>>2, col (c&3)*8
    // per-lane LDS byte addr = tid*16 -> wave-uniform base + lane*16  (required)
    const int c0 = tid, c1 = tid + 256;
    const int r0 = c0 >> 2, kk0 = (c0 & 3) << 3;
    const int r1 = c1 >> 2, kk1 = (c1 & 3) << 3;

    f32x4 acc[4][4];
#pragma unroll
    for (int m = 0; m < 4; ++m)
#pragma unroll
        for (int n = 0; n < 4; ++n)
            acc[m][n] = f32x4{0.f, 0.f, 0.f, 0.f};

    for (int k0 = 0; k0 < D_; k0 += 32) {
        gload_lds16(&Ab[(row0 + r0) * D_ + k0 + kk0], &As[r0][kk0]);
        gload_lds16(&Ab[(row0 + r1) * D_ + k0 + kk1], &As[r1][kk1]);
        gload_lds16(&Wb[(col0 + r0) * D_ + k0 + kk0], &Ws[r0][kk0]);
        gload_lds16(&Wb[(col0 + r1) * D_ + k0 + kk1], &Ws[r1][kk1]);
        __syncthreads();   // compiler drains vmcnt before s_barrier

        bf16x8 av[4], bv[4];
#pragma unroll
        for (int m = 0; m < 4; ++m)
            av[m] = *(const bf16x8*)&As[wr + m * 16 + lrow][k8];
#pragma unroll
        for (int n = 0; n < 4; ++n)
            bv[n] = *(const bf16x8*)&Ws[wc + n * 16 + lrow][k8];
#pragma unroll
        for (int m = 0; m < 4; ++m)
#pragma unroll
            for (int n = 0; n < 4; ++n)
                acc[m][n] = __builtin_amdgcn_mfma_f32_16x16x32_bf16(
                    av[m], bv[n], acc[m][n], 0, 0, 0);
        __syncthreads();
    }

    // C/D layout: col = lane&15, row = 4*(lane>>4) + reg   [m89-verified]
    const int rbase = (lane >> 4) << 2;
#pragma unroll
    for (int m = 0; m < 4; ++m)
#pragma unroll
        for (int n = 0; n < 4; ++n)
#pragma unroll
            for (int r = 0; r < 4; ++r)
                P[(row0 + wr + m * 16 + rbase + r) * D_ + col0 + wc + n * 16 + lrow] =
                    acc[m][n][r];
}

// ---- kernel 4: out[row] = P[idx[row]]  (float4 streaming copy) -------------

__global__ __launch_bounds__(256) void gather_kernel(
    const float* __restrict__ P, const int* __restrict__ idx,
    float* __restrict__ out) {
    const int total = NROWS * (D_ / 4);   // 8,388,608 float4s
    const float4* P4 = (const float4*)P;
    float4* O4 = (float4*)out;
    for (int v = blockIdx.x * 256 + threadIdx.x; v < total; v += gridDim.x * 256) {
        int row = v >> 8;      // 256 float4s per output row
        int c4 = v & 255;
        int s = idx[row];      // uniform within each 256-thread slice -> scalar load
        O4[v] = P4[s * 256 + c4];
    }
}

// ---- fallback (only if ws too small): direct fp32 compute ------------------

__global__ __launch_bounds__(256) void fallback_kernel(
    const int* __restrict__ t, const float* __restrict__ tab,
    const float* __restrict__ w, float* __restrict__ out) {
    __shared__ float emb[D_];
    int row = blockIdx.x;
    int j = row & (TT - 1);
    int cur = t[row];
    int prev = (j == 0) ? 0 : t[row - 1];
    int s = hash_pair(cur, prev);
    for (int d = threadIdx.x; d < D_; d += 256) emb[d] = tab[s * D_ + d];
    __syncthreads();
    for (int e = threadIdx.x; e < D_; e += 256) {
        float accv = 0.f;
        const float* wrow = &w[e * D_];
        for (int d = 0; d < D_; ++d) accv += emb[d] * wrow[d];
        out[(size_t)row * D_ + e] = accv;
    }
}

// ---- launch ---------------------------------------------------------------

extern "C" void kernel_launch(void* const* d_in, const int* in_sizes, int n_in,
                              void* d_out, int out_size, void* d_ws, size_t ws_size,
                              hipStream_t stream) {
    const int* t = (const int*)d_in[0];
    const float* tab = (const float*)d_in[1];
    const float* w = (const float*)d_in[2];
    float* out = (float*)d_out;

    const size_t off_tabb = 0;
    const size_t off_wb   = (size_t)SZ * D_ * 2;            //  6,291,456
    const size_t off_P    = off_wb + (size_t)D_ * D_ * 2;   //  8,388,608
    const size_t off_idx  = off_P + (size_t)SZ * D_ * 4;    // 20,971,520
    const size_t need     = off_idx + (size_t)NROWS * 4;    // 21,102,592

    if (ws_size < need) {
        fallback_kernel<<<NROWS, 256, 0, stream>>>(t, tab, w, out);
        return;
    }

    u16* tabb = (u16*)((char*)d_ws + off_tabb);
    u16* wb   = (u16*)((char*)d_ws + off_wb);
    float* P  = (float*)((char*)d_ws + off_P);
    int* idx  = (int*)((char*)d_ws + off_idx);

    convert_kernel<<<4096, 256, 0, stream>>>(tab, w, tabb, wb);
    hash_kernel<<<NROWS / 256, 256, 0, stream>>>(t, idx);
    gemm_p_kernel<<<(SZ / 128) * (D_ / 128), 256, 0, stream>>>(tabb, wb, P);
    gather_kernel<<<2048, 256, 0, stream>>>(P, idx, out);
}

// Round 6
// 188.914 us; speedup vs baseline: 1.0267x; 1.0267x over previous
//
#include <hip/hip_runtime.h>
#include <hip/hip_bf16.h>
#include <stdint.h>

#define SZ 3072
#define D_ 1024
#define BB 4
#define TT 8192
#define NROWS (BB * TT)   // 32768

typedef unsigned short u16;
typedef __bf16 bf16x8 __attribute__((ext_vector_type(8)));
typedef float f32x4 __attribute__((ext_vector_type(4)));

// ---- helpers ---------------------------------------------------------------

__device__ __forceinline__ u16 f2bf(float f) {
    union { float f; uint32_t u; } c;
    c.f = f;
    uint32_t u = c.u;
    // round-to-nearest-even f32 -> bf16 (inputs are finite Gaussians, no NaN)
    uint32_t r = (u + 0x7FFFu + ((u >> 16) & 1u)) >> 16;
    return (u16)r;
}

__device__ __forceinline__ void gload_lds16(const void* g, void* l) {
    // async global->LDS, 16B per lane. LDS dest must be wave-uniform base + lane*16.
    __builtin_amdgcn_global_load_lds(
        (__attribute__((address_space(1))) void*)(void*)g,
        (__attribute__((address_space(3))) void*)l,
        16, 0, 0);
}

__device__ __forceinline__ int hash_pair(int cur, int prev) {
    int a = (cur % SZ) * (31337 % SZ);      // 31337 % 3072 = 617
    int b = (prev % SZ) * (1000003 % SZ);   // 1000003 % 3072 = 1603
    return (a + b) % SZ;                    // max sum < 7M, int32-safe
}

// ---- kernel 1: fp32 -> bf16 convert of tab and w_proj ----------------------

__global__ __launch_bounds__(256) void convert_kernel(
    const float* __restrict__ tab, const float* __restrict__ w,
    u16* __restrict__ tabb, u16* __restrict__ wb) {
    const int NT4 = SZ * D_ / 4;        // 786432 float4s from tab
    const int NTOT = NT4 + D_ * D_ / 4; // + 262144 from w
    int i = blockIdx.x * 256 + threadIdx.x;
    if (i >= NTOT) return;
    const float4* src;
    u16* dst;
    int o;
    if (i < NT4) { src = (const float4*)tab; dst = tabb; o = i; }
    else         { src = (const float4*)w;   dst = wb;   o = i - NT4; }
    float4 v = src[o];
    unsigned long long pack =
        (unsigned long long)f2bf(v.x) |
        ((unsigned long long)f2bf(v.y) << 16) |
        ((unsigned long long)f2bf(v.z) << 32) |
        ((unsigned long long)f2bf(v.w) << 48);
    *(unsigned long long*)&dst[o * 4] = pack;
}

// ---- kernel 2: P[s,e] = sum_d tab[s,d] * w[e,d]  (bf16 MFMA, 64x64 tiles) --
// 768 blocks (3/CU co-resident) instead of 192: the small-GEMM regime is
// latency-bound, so occupancy (not schedule depth) is the lever.

__global__ __launch_bounds__(256) void gemm_p_kernel(
    const u16* __restrict__ Ab,   // [SZ][D_] bf16 bits
    const u16* __restrict__ Wb,   // [D_][D_] bf16 bits
    float* __restrict__ P) {      // [SZ][D_]
    __shared__ __align__(16) u16 As[64][32];
    __shared__ __align__(16) u16 Ws[64][32];

    // bijective XCD-chunked swizzle (nwg=768, 768%8==0): 96 consecutive
    // wgids per XCD -> 6 complete A-panel rows resident in one XCD L2.
    const int bid = blockIdx.x;
    const int wgid = (bid & 7) * 96 + (bid >> 3);
    const int brow = wgid >> 4;         // 48 row-tiles (64 rows each)
    const int bcol = wgid & 15;         // 16 col-tiles (64 cols each)
    const int row0 = brow << 6;
    const int col0 = bcol << 6;

    const int tid = threadIdx.x;
    const int lane = tid & 63;
    const int w = tid >> 6;             // wave 0..3 in 2x2 grid of 32x32 tiles
    const int wr = (w >> 1) << 5;
    const int wc = (w & 1) << 5;
    const int lrow = lane & 15;         // fragment row (A) / col (B/D)
    const int k8 = (lane >> 4) << 3;    // fragment k-offset

    // staging: 256 16B-chunks per operand (one per thread); chunk tid ->
    // row tid>>2, col (tid&3)*8. LDS byte addr = tid*16 (wave-uniform+lane*16).
    const int r0 = tid >> 2, kk0 = (tid & 3) << 3;

    f32x4 acc[2][2];
#pragma unroll
    for (int m = 0; m < 2; ++m)
#pragma unroll
        for (int n = 0; n < 2; ++n)
            acc[m][n] = f32x4{0.f, 0.f, 0.f, 0.f};

    for (int k0 = 0; k0 < D_; k0 += 32) {
        gload_lds16(&Ab[(row0 + r0) * D_ + k0 + kk0], &As[r0][kk0]);
        gload_lds16(&Wb[(col0 + r0) * D_ + k0 + kk0], &Ws[r0][kk0]);
        __syncthreads();   // compiler drains vmcnt before s_barrier

        bf16x8 av[2], bv[2];
#pragma unroll
        for (int m = 0; m < 2; ++m)
            av[m] = *(const bf16x8*)&As[wr + m * 16 + lrow][k8];
#pragma unroll
        for (int n = 0; n < 2; ++n)
            bv[n] = *(const bf16x8*)&Ws[wc + n * 16 + lrow][k8];
#pragma unroll
        for (int m = 0; m < 2; ++m)
#pragma unroll
            for (int n = 0; n < 2; ++n)
                acc[m][n] = __builtin_amdgcn_mfma_f32_16x16x32_bf16(
                    av[m], bv[n], acc[m][n], 0, 0, 0);
        __syncthreads();
    }

    // C/D layout: col = lane&15, row = 4*(lane>>4) + reg   [m89-verified]
    const int rbase = (lane >> 4) << 2;
#pragma unroll
    for (int m = 0; m < 2; ++m)
#pragma unroll
        for (int n = 0; n < 2; ++n)
#pragma unroll
            for (int r = 0; r < 4; ++r)
                P[(row0 + wr + m * 16 + rbase + r) * D_ + col0 + wc + n * 16 + lrow] =
                    acc[m][n][r];
}

// ---- kernel 3: out[row] = P[hash(t[row], t[row-1])]  (fused hash + gather) -

__global__ __launch_bounds__(256) void gather_kernel(
    const float* __restrict__ P, const int* __restrict__ t,
    float* __restrict__ out) {
    const int total = NROWS * (D_ / 4);   // 8,388,608 float4s
    const f32x4* P4 = (const f32x4*)P;
    f32x4* O4 = (f32x4*)out;
    for (int v = blockIdx.x * 256 + threadIdx.x; v < total; v += gridDim.x * 256) {
        int row = v >> 8;      // 256 float4s per output row; wave-uniform
        int c4 = v & 255;
        int cur = t[row];
        int prev = ((row & (TT - 1)) == 0) ? 0 : t[row - 1];
        int s = hash_pair(cur, prev);
        f32x4 val = P4[s * 256 + c4];
        // non-temporal: don't let the 128 MiB output stream evict P from L2
        __builtin_nontemporal_store(val, &O4[v]);
    }
}

// ---- fallback (only if ws too small): direct fp32 compute ------------------

__global__ __launch_bounds__(256) void fallback_kernel(
    const int* __restrict__ t, const float* __restrict__ tab,
    const float* __restrict__ w, float* __restrict__ out) {
    __shared__ float emb[D_];
    int row = blockIdx.x;
    int j = row & (TT - 1);
    int cur = t[row];
    int prev = (j == 0) ? 0 : t[row - 1];
    int s = hash_pair(cur, prev);
    for (int d = threadIdx.x; d < D_; d += 256) emb[d] = tab[s * D_ + d];
    __syncthreads();
    for (int e = threadIdx.x; e < D_; e += 256) {
        float accv = 0.f;
        const float* wrow = &w[e * D_];
        for (int d = 0; d < D_; ++d) accv += emb[d] * wrow[d];
        out[(size_t)row * D_ + e] = accv;
    }
}

// ---- launch ---------------------------------------------------------------

extern "C" void kernel_launch(void* const* d_in, const int* in_sizes, int n_in,
                              void* d_out, int out_size, void* d_ws, size_t ws_size,
                              hipStream_t stream) {
    const int* t = (const int*)d_in[0];
    const float* tab = (const float*)d_in[1];
    const float* w = (const float*)d_in[2];
    float* out = (float*)d_out;

    const size_t off_tabb = 0;
    const size_t off_wb   = (size_t)SZ * D_ * 2;            //  6,291,456
    const size_t off_P    = off_wb + (size_t)D_ * D_ * 2;   //  8,388,608
    const size_t need     = off_P + (size_t)SZ * D_ * 4;    // 20,971,520

    if (ws_size < need) {
        fallback_kernel<<<NROWS, 256, 0, stream>>>(t, tab, w, out);
        return;
    }

    u16* tabb = (u16*)((char*)d_ws + off_tabb);
    u16* wb   = (u16*)((char*)d_ws + off_wb);
    float* P  = (float*)((char*)d_ws + off_P);

    convert_kernel<<<4096, 256, 0, stream>>>(tab, w, tabb, wb);
    gemm_p_kernel<<<(SZ / 64) * (D_ / 64), 256, 0, stream>>>(tabb, wb, P);
    gather_kernel<<<2048, 256, 0, stream>>>(P, t, out);
}